// Round 5
// baseline (506.970 us; speedup 1.0000x reference)
//
#include <hip/hip_runtime.h>
#include <math.h>

#define NB0   2
#define CX    64
#define NSP   64000      // 40*40*40
#define NH    4
#define HD    32
#define NM    8
#define OUTC  256

typedef float f32x2 __attribute__((ext_vector_type(2)));

// workspace float offsets (doubles first, 8B aligned)
#define OFF_DMC    0        // double [2][64][8]  cond block means
#define OFF_CC     2048     // float  [8][8][32]  raw cond-centers
#define OFF_NUM    4096     // float  [8][8][32]
#define OFF_DEN    6144     // float  [8][8]
#define OFF_WCT    6208     // float  [64][128]   cond_enc_w transposed
#define OFF_WXT    14400    // float  [64][32][4] x_enc_w packed [i][c][e]
#define OFF_CNF    22592    // float  [8][8][32]  normalized x-centers (np-f32 replica)
#define OFF_PART   24640    // float  [8][8][32][400] run partials
#define OFF_SVAL   843840   // float  [8][64000]
#define OFF_SIDX   1355840  // int    [8][64000]
#define OFF_PW     1867840  // float  [2][256][32]

// numpy pairwise_sum, n==20 (r[j]=a[j]+a[8+j]; combine; tail 16..19)
__device__ __forceinline__ float pairwise20(const float* v) {
    float r[8];
    #pragma unroll
    for (int j = 0; j < 8; ++j) r[j] = __fadd_rn(v[j], v[8 + j]);
    float res = __fadd_rn(__fadd_rn(__fadd_rn(r[0], r[1]), __fadd_rn(r[2], r[3])),
                          __fadd_rn(__fadd_rn(r[4], r[5]), __fadd_rn(r[6], r[7])));
    res = __fadd_rn(res, v[16]);
    res = __fadd_rn(res, v[17]);
    res = __fadd_rn(res, v[18]);
    res = __fadd_rn(res, v[19]);
    return res;
}

// numpy pairwise_sum, n==32 (r[j]=a[j]+a[8+j]+a[16+j]+a[24+j]; combine)
__device__ __forceinline__ float pairwise32(const float* v) {
    float r[8];
    #pragma unroll
    for (int j = 0; j < 8; ++j)
        r[j] = __fadd_rn(__fadd_rn(__fadd_rn(v[j], v[8 + j]), v[16 + j]), v[24 + j]);
    return __fadd_rn(__fadd_rn(__fadd_rn(r[0], r[1]), __fadd_rn(r[2], r[3])),
                     __fadd_rn(__fadd_rn(r[4], r[5]), __fadd_rn(r[6], r[7])));
}

// numpy einsum sum_of_products f32, SSE baseline (4 lanes, 4 accumulators), n=32
__device__ __forceinline__ float einsum_dot32(const float* p) {
    float q[16];
    #pragma unroll
    for (int k = 0; k < 4; ++k) {
        #pragma unroll
        for (int l = 0; l < 4; ++l)
            q[k * 4 + l] = __fadd_rn(p[4 * k + l], p[16 + 4 * k + l]);
    }
    float rv[4];
    #pragma unroll
    for (int l = 0; l < 4; ++l)
        rv[l] = __fadd_rn(__fadd_rn(q[l], q[4 + l]), __fadd_rn(q[8 + l], q[12 + l]));
    return __fadd_rn(__fadd_rn(rv[0], rv[2]), __fadd_rn(rv[1], rv[3]));
}

// ------- cond transpose [128,64]->[64,128]; x pack [128,64]->[64][32][4] ----
__global__ void transpose_k(const float* __restrict__ cw, const float* __restrict__ xw,
                            float* __restrict__ wct, float* __restrict__ wp4) {
    int idx = blockIdx.x * 256 + threadIdx.x;   // 16384
    int sel = idx >> 13;
    int j = idx & 8191;
    if (sel == 0) {
        int i = j >> 7, o = j & 127;
        wct[j] = cw[o * 64 + i];
    } else {
        // j = (i*32 + c)*4 + e  <-  xw[(e*32+c)*64 + i]
        int e = j & 3; int t = j >> 2; int c = t & 31; int i = t >> 5;
        wp4[j] = xw[(e * 32 + c) * 64 + i];
    }
}

// ------- block means (f64) of cond over 20x20x20 blocks (smooth path) -------
__global__ __launch_bounds__(256) void pool_cond_k(const float* __restrict__ cond,
                                                   double* __restrict__ cmean) {
    int bx = blockIdx.x;                 // (b0*64+i)*4 + (hb*2+wb)
    int wh = bx & 3; int hb = wh >> 1; int wb = wh & 1;
    int i   = (bx >> 2) & 63;
    int b0  = bx >> 8;
    const float* src = cond + (size_t)(b0 * CX + i) * NSP + hb * 20 * 1600 + wb * 20 * 40;
    double s0 = 0.0, s1 = 0.0;
    for (int cell = threadIdx.x; cell < 400; cell += 256) {
        int hl = cell / 20, wl = cell - hl * 20;
        const float4* rp = (const float4*)(src + hl * 1600 + wl * 40);
        #pragma unroll
        for (int q = 0; q < 5; ++q) {
            float4 v = rp[q];
            s0 += (double)v.x; s0 += (double)v.y; s0 += (double)v.z; s0 += (double)v.w;
        }
        #pragma unroll
        for (int q = 5; q < 10; ++q) {
            float4 v = rp[q];
            s1 += (double)v.x; s1 += (double)v.y; s1 += (double)v.z; s1 += (double)v.w;
        }
    }
    #pragma unroll
    for (int k = 32; k > 0; k >>= 1) { s0 += __shfl_down(s0, k); s1 += __shfl_down(s1, k); }
    __shared__ double r0[4], r1[4];
    int wid = threadIdx.x >> 6, lane = threadIdx.x & 63;
    if (lane == 0) { r0[wid] = s0; r1[wid] = s1; }
    __syncthreads();
    if (threadIdx.x == 0) {
        double t0 = r0[0] + r0[1] + r0[2] + r0[3];
        double t1 = r1[0] + r1[1] + r1[2] + r1[3];
        double* dst = cmean + b0 * 512 + i * 8 + wb * 4 + hb * 2;  // m = wb*4+hb*2+db
        dst[0] = t0 * (1.0 / 8000.0);
        dst[1] = t1 * (1.0 / 8000.0);
    }
}

// ------- cond centers cc = enc(mean) (smooth path, f64 then f32) ------------
__global__ void cc_centers_k(const double* __restrict__ cmean,
                             const float* __restrict__ cw, const float* __restrict__ cb,
                             float* __restrict__ cc) {
    int bx = blockIdx.x;                 // b*8 + m
    int m = bx & 7; int b = bx >> 3; int b0 = b >> 2; int e = b & 3;
    int c = threadIdx.x;                 // 0..31
    int o = e * 32 + c;
    double sc = (double)cb[o];
    for (int i = 0; i < 64; ++i)
        sc = fma((double)cw[o * 64 + i], cmean[b0 * 512 + i * 8 + m], sc);
    cc[(b * 8 + m) * 32 + c] = (float)sc;
}

// ---- np-f32 replica: x_feat + pairwise20 run-partials, LDS-staged ----------
// grid 800 = (b0*8 + m)*50 + chunk; block 256 = (rg 0..7) x (c 0..31)
// Each thread computes ALL 4 heads (acc[4][20]) so x is fetched from HBM once.
// NOTE: argmax-critical path — ONLY __fadd_rn/__fmul_rn, i ascending, bias
// LAST, pairwise20.
__global__ __launch_bounds__(256, 3) void xfeat_partial_k(
        const float* __restrict__ x, const float* __restrict__ wp4,
        const float* __restrict__ xb, float* __restrict__ partial) {
    __shared__ float xs[512 * 20];       // 40 KB: row (i*8+rg), 20 floats each
    int bx = blockIdx.x;
    int chunk = bx % 50; int t2 = bx / 50;
    int m  = t2 & 7;
    int b0 = t2 >> 3;
    int qw = m >> 2, qh = (m >> 1) & 1, qd = m & 1;
    int tid = threadIdx.x;
    int lane = tid & 63, wid = tid >> 6;

    // ---- stage 40KB x tile (2560 16B slots, 40 wave-instrs over 4 waves) ----
    const float* xbase = x + (size_t)(b0 * CX) * NSP;
    for (int j = wid; j < 40; j += 4) {
        int slot = j * 64 + lane;        // = row*5 + p ; LDS byte off = slot*16
        int row = slot / 5;              // row = i*8 + rg
        int p   = slot - row * 5;
        int i   = row >> 3;
        int rg  = row & 7;
        int rglob = chunk * 8 + rg;      // 0..399, = wl*20 + hl
        int wl = rglob / 20, hl = rglob - wl * 20;
        const float* gp = xbase + (size_t)i * NSP
                        + (qh * 20 + hl) * 1600 + (qw * 20 + wl) * 40 + qd * 20 + p * 4;
        __builtin_amdgcn_global_load_lds(
            (const __attribute__((address_space(1))) void*)gp,
            (__attribute__((address_space(3))) void*)(xs + slot * 4),
            16, 0, 0);
    }
    __syncthreads();                     // drains vmcnt before LDS reads

    int c  = tid & 31;
    int rg = tid >> 5;                   // 0..7

    float acc[4][20];
    #pragma unroll
    for (int e = 0; e < 4; ++e)
        #pragma unroll
        for (int d = 0; d < 20; ++d) acc[e][d] = 0.f;

    const float* xrow0 = xs + rg * 20;
    for (int i = 0; i < 64; ++i) {
        float4 wv = *(const float4*)(wp4 + ((i * 32 + c) << 2));  // [i][c][e], L2-hot
        float xv[20];
        #pragma unroll
        for (int dd = 0; dd < 5; ++dd)
            *(float4*)(xv + dd * 4) = *(const float4*)(xrow0 + i * 160 + dd * 4);
        #pragma unroll
        for (int d = 0; d < 20; ++d) {   // np order: mul then add, i ascending
            acc[0][d] = __fadd_rn(acc[0][d], __fmul_rn(wv.x, xv[d]));
            acc[1][d] = __fadd_rn(acc[1][d], __fmul_rn(wv.y, xv[d]));
            acc[2][d] = __fadd_rn(acc[2][d], __fmul_rn(wv.z, xv[d]));
            acc[3][d] = __fadd_rn(acc[3][d], __fmul_rn(wv.w, xv[d]));
        }
    }

    int rglob = chunk * 8 + rg;
    size_t obase = ((size_t)((b0 * 4) * 8 + m) * 32 + c) * 400 + rglob;
    #pragma unroll
    for (int e = 0; e < 4; ++e) {
        float bias = xb[e * 32 + c];
        float feat[20];
        #pragma unroll
        for (int d = 0; d < 20; ++d) feat[d] = __fadd_rn(acc[e][d], bias);  // bias LAST
        partial[obase + (size_t)e * 102400] = pairwise20(feat);
    }
}

// ---- np-f32 replica: 400-run chain (h-inner,w-outer order) + mean + l2norm -
__global__ void xcenters_k(const float* __restrict__ partial, float* __restrict__ cnf) {
    int bx = blockIdx.x;                 // b*8 + m
    int c = threadIdx.x;                 // 0..31
    const float* pp = partial + ((size_t)(bx * 32 + c)) * 400;
    float acc = 0.f;
    for (int r = 0; r < 400; ++r) acc = __fadd_rn(acc, pp[r]);   // r ascending
    float mean = __fdiv_rn(acc, 8000.0f);
    __shared__ float mm[32];
    mm[c] = mean;
    __syncthreads();
    float sq[32];
    #pragma unroll
    for (int j = 0; j < 32; ++j) sq[j] = __fmul_rn(mm[j], mm[j]);
    float nrm = fmaxf(__fsqrt_rn(pairwise32(sq)), 1e-12f);
    cnf[bx * 32 + c] = __fdiv_rn(mean, nrm);
}

// ---- fused: np-f32-replica cond encode + l2norm + sim/argmax + num/den -----
// grid 1000 = b0*500 + grp; 128 voxels per block; wave e handles head e;
// lane spL owns voxel PAIR (2*spL, 2*spL+1) -> per-iter VALU work doubles to
// 256 cyc per wave, fully covering the ~250-300cy s_load weight-row latency
// that R4's counters exposed (21% VALUBusy, lgkm-stalled). Two independent
// scalar accumulator chains per lane (acc0/acc1), each bit-identical to the
// proven FP DAG (i ascending, __fmul_rn/__fadd_rn, bias LAST). No inline asm.
#define DOWNSTREAM(ACC, V)                                                    \
    {                                                                         \
        float a[32];                                                          \
        _Pragma("unroll")                                                     \
        for (int j = 0; j < 32; ++j) a[j] = __fadd_rn(ACC[j], bp[j]);         \
        float sq[32];                                                         \
        _Pragma("unroll")                                                     \
        for (int j = 0; j < 32; ++j) sq[j] = __fmul_rn(a[j], a[j]);           \
        float nrm = fmaxf(__fsqrt_rn(pairwise32(sq)), 1e-12f);                \
        float u[32];                                                          \
        _Pragma("unroll")                                                     \
        for (int j = 0; j < 32; ++j) u[j] = __fdiv_rn(a[j], nrm);             \
        float bs = -1.0f; int bi = 0;                                         \
        _Pragma("unroll")                                                     \
        for (int mi = 0; mi < 8; ++mi) {                                      \
            float pr[32];                                                     \
            _Pragma("unroll")                                                 \
            for (int j = 0; j < 32; ++j)                                      \
                pr[j] = __fmul_rn(cnp[mi * 32 + j], u[j]);                    \
            float dot = einsum_dot32(pr);                                     \
            float z = __fadd_rn(beta, __fmul_rn(alpha, dot));                 \
            float sm = (float)(1.0 / (1.0 + exp(-(double)z)));                \
            if (sm > bs) { bs = sm; bi = mi; }                                \
        }                                                                     \
        float s = bs;                                                         \
        int sp = sp0 + 2 * spL + (V);                                         \
        int h = sp / 1600;                                                    \
        int rem = sp - h * 1600;                                              \
        int w = rem / 40;                                                     \
        int d = rem - w * 40;                                                 \
        int n = w * 1600 + h * 40 + d;                                        \
        int b = b0 * 4 + e;                                                   \
        sval[b * NSP + n] = s;                                                \
        sidx[b * NSP + n] = bi;                                               \
        float* al = &agg[(e * 8 + bi) * 32];                                  \
        _Pragma("unroll")                                                     \
        for (int j = 0; j < 32; ++j) atomicAdd(&al[j], s * a[j]);             \
        atomicAdd(&agg[1024 + e * 8 + bi], s);                                \
    }

__global__ __launch_bounds__(256, 3) void fused_enc_sim_k(
        const float* __restrict__ cond, const float* __restrict__ wct,
        const float* __restrict__ cnf, const float* __restrict__ cbias,
        const float* __restrict__ alpha_p, const float* __restrict__ beta_p,
        float* __restrict__ sval, int* __restrict__ sidx,
        float* __restrict__ num, float* __restrict__ den) {
    __shared__ float xs[8192];           // [i][vox] cond tile 32KB; reused as agg
    __shared__ float cns[1024];          // [e][m][c]
    int tid = threadIdx.x;
    int bx  = blockIdx.x;
    int b0  = bx / 500;
    int grp = bx - b0 * 500;
    int sp0 = grp * 128;
    int spL = tid & 63;
    int lane = tid & 63, wid = tid >> 6;
    int e = __builtin_amdgcn_readfirstlane(tid >> 6);
    float alpha = alpha_p[0], beta = beta_p[0];
    const float* wt = wct + e * 32;      // wave-uniform -> scalar loads
    const float* bp = cbias + e * 32;

    // ---- stage cond tile [64 ch][128 vox] (2048 16B slots, 8 instrs/wave) --
    const float* cbase = cond + (size_t)b0 * CX * NSP + sp0;
    for (int j = wid; j < 32; j += 4) {
        int slot = j * 64 + lane;        // LDS byte off = slot*16 (linear, m104)
        int i  = slot >> 5;              // channel (32 slots per 512B row)
        int vq = slot & 31;              // 16B chunk within row
        const float* gp = cbase + (size_t)i * NSP + vq * 4;
        __builtin_amdgcn_global_load_lds(
            (const __attribute__((address_space(1))) void*)gp,
            (__attribute__((address_space(3))) void*)(xs + slot * 4),
            16, 0, 0);
    }
    for (int t = tid; t < 1024; t += 256) cns[t] = cnf[b0 * 1024 + t];
    const float* cnp = cns + e * 256;
    __syncthreads();                     // drains vmcnt; tile + cns ready

    // np einsum order: acc=0; += w*x via separate mul,add (intrinsics — NO FMA)
    float acc0[32], acc1[32];
    #pragma unroll
    for (int j = 0; j < 32; ++j) { acc0[j] = 0.f; acc1[j] = 0.f; }
    for (int i = 0; i < 64; ++i) {
        f32x2 xv2 = *(const f32x2*)(xs + i * 128 + 2 * spL);   // ds_read_b64
        const float* wr = wt + i * 128;
        #pragma unroll
        for (int j = 0; j < 32; ++j) {
            acc0[j] = __fadd_rn(acc0[j], __fmul_rn(wr[j], xv2.x));
            acc1[j] = __fadd_rn(acc1[j], __fmul_rn(wr[j], xv2.y));
        }
    }

    __syncthreads();                     // all tile reads done -> reuse xs as agg
    float* agg = xs;                     // [e][m][c] 1024 + den [e][m] 32
    for (int t = tid; t < 1056; t += 256) agg[t] = 0.f;
    __syncthreads();

    DOWNSTREAM(acc0, 0)
    DOWNSTREAM(acc1, 1)

    __syncthreads();
    for (int t = tid; t < 1056; t += 256) {
        float v = agg[t];
        if (t < 1024) atomicAdd(&num[b0 * 1024 + t], v);
        else          atomicAdd(&den[b0 * 32 + (t - 1024)], v);
    }
}

// ---------- w = (num+cc)/(den+1); PW[b0][o][e*8+m] = proj_w . w -------------
__global__ void wproj_k(const float* __restrict__ num, const float* __restrict__ cc,
                        const float* __restrict__ den, const float* __restrict__ pwm,
                        float* __restrict__ pw_out) {
    int bx = blockIdx.x;                 // b0*256 + o
    int b0 = bx >> 8; int o = bx & 255;
    int t = threadIdx.x;                 // 0..31 = e*8+m
    int e = t >> 3, m = t & 7;
    int b = b0 * 4 + e;
    float dv = den[b * 8 + m] + 1.0f;
    float acc = 0.f;
    for (int c = 0; c < 32; ++c)
        acc = fmaf(pwm[o * 128 + e * 32 + c],
                   num[(b * 8 + m) * 32 + c] + cc[(b * 8 + m) * 32 + c], acc);
    pw_out[(b0 * 256 + o) * 32 + t] = acc / dv;
}

// ---------- out[b0,o,n] = pb[o] + sum_e s_e * PW[o][e*8+idx_e] --------------
// grid 1000 = b0*500 + oh*250 + chunk (o split in halves of 128)
__global__ __launch_bounds__(256) void out_proj_k(
        const float* __restrict__ sval, const int* __restrict__ sidx,
        const float* __restrict__ pw, const float* __restrict__ pb,
        float* __restrict__ out) {
    __shared__ float pwl[4096];          // [128 o][32]
    int tid = threadIdx.x;
    int bx  = blockIdx.x;
    int b0  = bx / 500;
    int r   = bx - b0 * 500;
    int oh  = r / 250;
    int chunk = r - oh * 250;
    int n = chunk * 256 + tid;
    for (int k = 0; k < 16; ++k)
        pwl[k * 256 + tid] = pw[b0 * 8192 + oh * 4096 + k * 256 + tid];
    float s0 = sval[(b0 * 4 + 0) * NSP + n]; int j0 = 0  + sidx[(b0 * 4 + 0) * NSP + n];
    float s1 = sval[(b0 * 4 + 1) * NSP + n]; int j1 = 8  + sidx[(b0 * 4 + 1) * NSP + n];
    float s2 = sval[(b0 * 4 + 2) * NSP + n]; int j2 = 16 + sidx[(b0 * 4 + 2) * NSP + n];
    float s3 = sval[(b0 * 4 + 3) * NSP + n]; int j3 = 24 + sidx[(b0 * 4 + 3) * NSP + n];
    __syncthreads();
    float* ob = out + (size_t)b0 * OUTC * NSP + (size_t)oh * 128 * NSP + n;
    const float* pbh = pb + oh * 128;
    #pragma unroll 4
    for (int o = 0; o < 128; ++o) {
        const float* prw = &pwl[o * 32];
        float v = pbh[o];
        v = fmaf(s0, prw[j0], v);
        v = fmaf(s1, prw[j1], v);
        v = fmaf(s2, prw[j2], v);
        v = fmaf(s3, prw[j3], v);
        ob[(size_t)o * NSP] = v;
    }
}

extern "C" void kernel_launch(void* const* d_in, const int* in_sizes, int n_in,
                              void* d_out, int out_size, void* d_ws, size_t ws_size,
                              hipStream_t stream) {
    const float* x     = (const float*)d_in[0];
    const float* cond  = (const float*)d_in[1];
    const float* xw    = (const float*)d_in[2];
    const float* xb    = (const float*)d_in[3];
    const float* cw    = (const float*)d_in[4];
    const float* cb    = (const float*)d_in[5];
    const float* alpha = (const float*)d_in[6];
    const float* beta  = (const float*)d_in[7];
    const float* pwm   = (const float*)d_in[8];
    const float* pb    = (const float*)d_in[9];
    float* out = (float*)d_out;
    float* wsf = (float*)d_ws;

    double* dmc = (double*)(wsf + OFF_DMC);
    float* cc   = wsf + OFF_CC;
    float* num  = wsf + OFF_NUM;
    float* den  = wsf + OFF_DEN;
    float* wct  = wsf + OFF_WCT;
    float* wp4  = wsf + OFF_WXT;
    float* cnf  = wsf + OFF_CNF;
    float* part = wsf + OFF_PART;
    float* sv   = wsf + OFF_SVAL;
    int*   si   = (int*)(wsf + OFF_SIDX);
    float* pwq  = wsf + OFF_PW;

    hipMemsetAsync(num, 0, (2048 + 64) * sizeof(float), stream);   // num+den contiguous
    transpose_k<<<64, 256, 0, stream>>>(cw, xw, wct, wp4);
    pool_cond_k<<<512, 256, 0, stream>>>(cond, dmc);
    cc_centers_k<<<64, 32, 0, stream>>>(dmc, cw, cb, cc);
    xfeat_partial_k<<<800, 256, 0, stream>>>(x, wp4, xb, part);
    xcenters_k<<<64, 32, 0, stream>>>(part, cnf);
    fused_enc_sim_k<<<1000, 256, 0, stream>>>(cond, wct, cnf, cb, alpha, beta, sv, si, num, den);
    wproj_k<<<512, 32, 0, stream>>>(num, cc, den, pwm, pwq);
    out_proj_k<<<1000, 256, 0, stream>>>(sv, si, pwq, pb, out);
}

// Round 6
// 385.910 us; speedup vs baseline: 1.3137x; 1.3137x over previous
//
#include <hip/hip_runtime.h>
#include <math.h>

#define NB0   2
#define CX    64
#define NSP   64000      // 40*40*40
#define NH    4
#define HD    32
#define NM    8
#define OUTC  256

// workspace float offsets (doubles first, 8B aligned)
#define OFF_DMC    0        // double [2][64][8]  cond block means
#define OFF_CC     2048     // float  [8][8][32]  raw cond-centers
#define OFF_NUM    4096     // float  [8][8][32]
#define OFF_DEN    6144     // float  [8][8]
#define OFF_WCT    6208     // float  [64][128]   cond_enc_w transposed
#define OFF_WXT    14400    // float  [64][32][4] x_enc_w packed [i][c][e]
#define OFF_CNF    22592    // float  [8][8][32]  normalized x-centers (np-f32 replica)
#define OFF_PART   24640    // float  [8][8][32][400] run partials; numR aliases (dead after xcenters_k)
#define OFF_SVAL   843840   // float  [8][64000]
#define OFF_SIDX   1355840  // int    [8][64000]
#define OFF_PW     1867840  // float  [2][256][32]

// numpy pairwise_sum, n==20 (r[j]=a[j]+a[8+j]; combine; tail 16..19)
__device__ __forceinline__ float pairwise20(const float* v) {
    float r[8];
    #pragma unroll
    for (int j = 0; j < 8; ++j) r[j] = __fadd_rn(v[j], v[8 + j]);
    float res = __fadd_rn(__fadd_rn(__fadd_rn(r[0], r[1]), __fadd_rn(r[2], r[3])),
                          __fadd_rn(__fadd_rn(r[4], r[5]), __fadd_rn(r[6], r[7])));
    res = __fadd_rn(res, v[16]);
    res = __fadd_rn(res, v[17]);
    res = __fadd_rn(res, v[18]);
    res = __fadd_rn(res, v[19]);
    return res;
}

// numpy pairwise_sum, n==32 (r[j]=a[j]+a[8+j]+a[16+j]+a[24+j]; combine)
__device__ __forceinline__ float pairwise32(const float* v) {
    float r[8];
    #pragma unroll
    for (int j = 0; j < 8; ++j)
        r[j] = __fadd_rn(__fadd_rn(__fadd_rn(v[j], v[8 + j]), v[16 + j]), v[24 + j]);
    return __fadd_rn(__fadd_rn(__fadd_rn(r[0], r[1]), __fadd_rn(r[2], r[3])),
                     __fadd_rn(__fadd_rn(r[4], r[5]), __fadd_rn(r[6], r[7])));
}

// numpy einsum sum_of_products f32, SSE baseline (4 lanes, 4 accumulators), n=32
__device__ __forceinline__ float einsum_dot32(const float* p) {
    float q[16];
    #pragma unroll
    for (int k = 0; k < 4; ++k) {
        #pragma unroll
        for (int l = 0; l < 4; ++l)
            q[k * 4 + l] = __fadd_rn(p[4 * k + l], p[16 + 4 * k + l]);
    }
    float rv[4];
    #pragma unroll
    for (int l = 0; l < 4; ++l)
        rv[l] = __fadd_rn(__fadd_rn(q[l], q[4 + l]), __fadd_rn(q[8 + l], q[12 + l]));
    return __fadd_rn(__fadd_rn(rv[0], rv[2]), __fadd_rn(rv[1], rv[3]));
}

// ------- cond transpose [128,64]->[64,128]; x pack [128,64]->[64][32][4] ----
__global__ void transpose_k(const float* __restrict__ cw, const float* __restrict__ xw,
                            float* __restrict__ wct, float* __restrict__ wp4) {
    int idx = blockIdx.x * 256 + threadIdx.x;   // 16384
    int sel = idx >> 13;
    int j = idx & 8191;
    if (sel == 0) {
        int i = j >> 7, o = j & 127;
        wct[j] = cw[o * 64 + i];
    } else {
        // j = (i*32 + c)*4 + e  <-  xw[(e*32+c)*64 + i]
        int e = j & 3; int t = j >> 2; int c = t & 31; int i = t >> 5;
        wp4[j] = xw[(e * 32 + c) * 64 + i];
    }
}

// ------- block means (f64) of cond over 20x20x20 blocks (smooth path) -------
__global__ __launch_bounds__(256) void pool_cond_k(const float* __restrict__ cond,
                                                   double* __restrict__ cmean) {
    int bx = blockIdx.x;                 // (b0*64+i)*4 + (hb*2+wb)
    int wh = bx & 3; int hb = wh >> 1; int wb = wh & 1;
    int i   = (bx >> 2) & 63;
    int b0  = bx >> 8;
    const float* src = cond + (size_t)(b0 * CX + i) * NSP + hb * 20 * 1600 + wb * 20 * 40;
    double s0 = 0.0, s1 = 0.0;
    for (int cell = threadIdx.x; cell < 400; cell += 256) {
        int hl = cell / 20, wl = cell - hl * 20;
        const float4* rp = (const float4*)(src + hl * 1600 + wl * 40);
        #pragma unroll
        for (int q = 0; q < 5; ++q) {
            float4 v = rp[q];
            s0 += (double)v.x; s0 += (double)v.y; s0 += (double)v.z; s0 += (double)v.w;
        }
        #pragma unroll
        for (int q = 5; q < 10; ++q) {
            float4 v = rp[q];
            s1 += (double)v.x; s1 += (double)v.y; s1 += (double)v.z; s1 += (double)v.w;
        }
    }
    #pragma unroll
    for (int k = 32; k > 0; k >>= 1) { s0 += __shfl_down(s0, k); s1 += __shfl_down(s1, k); }
    __shared__ double r0[4], r1[4];
    int wid = threadIdx.x >> 6, lane = threadIdx.x & 63;
    if (lane == 0) { r0[wid] = s0; r1[wid] = s1; }
    __syncthreads();
    if (threadIdx.x == 0) {
        double t0 = r0[0] + r0[1] + r0[2] + r0[3];
        double t1 = r1[0] + r1[1] + r1[2] + r1[3];
        double* dst = cmean + b0 * 512 + i * 8 + wb * 4 + hb * 2;  // m = wb*4+hb*2+db
        dst[0] = t0 * (1.0 / 8000.0);
        dst[1] = t1 * (1.0 / 8000.0);
    }
}

// ------- cond centers cc = enc(mean) (smooth path, f64 then f32) ------------
__global__ void cc_centers_k(const double* __restrict__ cmean,
                             const float* __restrict__ cw, const float* __restrict__ cb,
                             float* __restrict__ cc) {
    int bx = blockIdx.x;                 // b*8 + m
    int m = bx & 7; int b = bx >> 3; int b0 = b >> 2; int e = b & 3;
    int c = threadIdx.x;                 // 0..31
    int o = e * 32 + c;
    double sc = (double)cb[o];
    for (int i = 0; i < 64; ++i)
        sc = fma((double)cw[o * 64 + i], cmean[b0 * 512 + i * 8 + m], sc);
    cc[(b * 8 + m) * 32 + c] = (float)sc;
}

// ---- np-f32 replica: x_feat + pairwise20 run-partials, LDS-staged ----------
// grid 800 = (b0*8 + m)*50 + chunk; block 256 = (rg 0..7) x (c 0..31)
// Each thread computes ALL 4 heads (acc[4][20]) so x is fetched from HBM once.
// NOTE: argmax-critical path — ONLY __fadd_rn/__fmul_rn, i ascending, bias
// LAST, pairwise20.
__global__ __launch_bounds__(256, 3) void xfeat_partial_k(
        const float* __restrict__ x, const float* __restrict__ wp4,
        const float* __restrict__ xb, float* __restrict__ partial) {
    __shared__ float xs[512 * 20];       // 40 KB: row (i*8+rg), 20 floats each
    int bx = blockIdx.x;
    int chunk = bx % 50; int t2 = bx / 50;
    int m  = t2 & 7;
    int b0 = t2 >> 3;
    int qw = m >> 2, qh = (m >> 1) & 1, qd = m & 1;
    int tid = threadIdx.x;
    int lane = tid & 63, wid = tid >> 6;

    // ---- stage 40KB x tile (2560 16B slots, 40 wave-instrs over 4 waves) ----
    const float* xbase = x + (size_t)(b0 * CX) * NSP;
    for (int j = wid; j < 40; j += 4) {
        int slot = j * 64 + lane;        // = row*5 + p ; LDS byte off = slot*16
        int row = slot / 5;              // row = i*8 + rg
        int p   = slot - row * 5;
        int i   = row >> 3;
        int rg  = row & 7;
        int rglob = chunk * 8 + rg;      // 0..399, = wl*20 + hl
        int wl = rglob / 20, hl = rglob - wl * 20;
        const float* gp = xbase + (size_t)i * NSP
                        + (qh * 20 + hl) * 1600 + (qw * 20 + wl) * 40 + qd * 20 + p * 4;
        __builtin_amdgcn_global_load_lds(
            (const __attribute__((address_space(1))) void*)gp,
            (__attribute__((address_space(3))) void*)(xs + slot * 4),
            16, 0, 0);
    }
    __syncthreads();                     // drains vmcnt before LDS reads

    int c  = tid & 31;
    int rg = tid >> 5;                   // 0..7

    float acc[4][20];
    #pragma unroll
    for (int e = 0; e < 4; ++e)
        #pragma unroll
        for (int d = 0; d < 20; ++d) acc[e][d] = 0.f;

    const float* xrow0 = xs + rg * 20;
    for (int i = 0; i < 64; ++i) {
        float4 wv = *(const float4*)(wp4 + ((i * 32 + c) << 2));  // [i][c][e], L2-hot
        float xv[20];
        #pragma unroll
        for (int dd = 0; dd < 5; ++dd)
            *(float4*)(xv + dd * 4) = *(const float4*)(xrow0 + i * 160 + dd * 4);
        #pragma unroll
        for (int d = 0; d < 20; ++d) {   // np order: mul then add, i ascending
            acc[0][d] = __fadd_rn(acc[0][d], __fmul_rn(wv.x, xv[d]));
            acc[1][d] = __fadd_rn(acc[1][d], __fmul_rn(wv.y, xv[d]));
            acc[2][d] = __fadd_rn(acc[2][d], __fmul_rn(wv.z, xv[d]));
            acc[3][d] = __fadd_rn(acc[3][d], __fmul_rn(wv.w, xv[d]));
        }
    }

    int rglob = chunk * 8 + rg;
    size_t obase = ((size_t)((b0 * 4) * 8 + m) * 32 + c) * 400 + rglob;
    #pragma unroll
    for (int e = 0; e < 4; ++e) {
        float bias = xb[e * 32 + c];
        float feat[20];
        #pragma unroll
        for (int d = 0; d < 20; ++d) feat[d] = __fadd_rn(acc[e][d], bias);  // bias LAST
        partial[obase + (size_t)e * 102400] = pairwise20(feat);
    }
}

// ---- np-f32 replica: 400-run chain (h-inner,w-outer order) + mean + l2norm -
__global__ void xcenters_k(const float* __restrict__ partial, float* __restrict__ cnf) {
    int bx = blockIdx.x;                 // b*8 + m
    int c = threadIdx.x;                 // 0..31
    const float* pp = partial + ((size_t)(bx * 32 + c)) * 400;
    float acc = 0.f;
    for (int r = 0; r < 400; ++r) acc = __fadd_rn(acc, pp[r]);   // r ascending
    float mean = __fdiv_rn(acc, 8000.0f);
    __shared__ float mm[32];
    mm[c] = mean;
    __syncthreads();
    float sq[32];
    #pragma unroll
    for (int j = 0; j < 32; ++j) sq[j] = __fmul_rn(mm[j], mm[j]);
    float nrm = fmaxf(__fsqrt_rn(pairwise32(sq)), 1e-12f);
    cnf[bx * 32 + c] = __fdiv_rn(mean, nrm);
}

// ---- fused: np-f32-replica cond encode + l2norm + sim/argmax + num/den -----
// grid 2000 = b0*1000 + grp (64 voxels per block; wave e handles head e).
// Proven R4 FP DAG, untouched. ONLY change: the global num/den atomic epilogue
// now targets replica (bx & 31) of numR[32][2][1056] — breaks the 1000-deep
// same-address atomic RMW chains (the measured ~140us invariant floor) into
// ~31-deep chains. reduce_nr_k folds replicas afterwards (order free — atomic
// order was already nondeterministic).
__global__ __launch_bounds__(256, 3) void fused_enc_sim_k(
        const float* __restrict__ cond, const float* __restrict__ wct,
        const float* __restrict__ cnf, const float* __restrict__ cbias,
        const float* __restrict__ alpha_p, const float* __restrict__ beta_p,
        float* __restrict__ sval, int* __restrict__ sidx,
        float* __restrict__ numR) {
    __shared__ float xs[4096];           // [i][vox] cond tile 16KB; reused as agg
    __shared__ float cns[1024];          // [e][m][c]
    int tid = threadIdx.x;
    int bx  = blockIdx.x;
    int b0  = bx / 1000;
    int grp = bx - b0 * 1000;
    int sp0 = grp * 64;
    int spL = tid & 63;
    int lane = tid & 63, wid = tid >> 6;
    int e = __builtin_amdgcn_readfirstlane(tid >> 6);
    float alpha = alpha_p[0], beta = beta_p[0];
    const float* wt = wct + e * 32;      // wave-uniform -> scalar loads
    const float* bp = cbias + e * 32;

    // ---- stage cond tile [64 ch][64 vox] (1024 16B slots, 4 instrs/wave) ----
    const float* cbase = cond + (size_t)b0 * CX * NSP + sp0;
    for (int j = wid; j < 16; j += 4) {
        int slot = j * 64 + lane;        // LDS byte off = slot*16 (linear, m104)
        int i  = slot >> 4;              // channel (16 slots per 256B row)
        int vq = slot & 15;              // 16B chunk within row
        const float* gp = cbase + (size_t)i * NSP + vq * 4;
        __builtin_amdgcn_global_load_lds(
            (const __attribute__((address_space(1))) void*)gp,
            (__attribute__((address_space(3))) void*)(xs + slot * 4),
            16, 0, 0);
    }
    for (int t = tid; t < 1024; t += 256) cns[t] = cnf[b0 * 1024 + t];
    const float* cnp = cns + e * 256;
    __syncthreads();                     // drains vmcnt; tile + cns ready

    // np einsum order: acc=0; += w*x via separate mul,add (intrinsics — NO FMA)
    float acc[32];
    #pragma unroll
    for (int j = 0; j < 32; ++j) acc[j] = 0.f;
    for (int i = 0; i < 64; ++i) {
        float xv = xs[i * 64 + spL];     // ds_read_b32, 2 lanes/bank = free
        const float* wr = wt + i * 128;
        #pragma unroll
        for (int j = 0; j < 32; ++j) acc[j] = __fadd_rn(acc[j], __fmul_rn(wr[j], xv));
    }
    #pragma unroll
    for (int j = 0; j < 32; ++j) acc[j] = __fadd_rn(acc[j], bp[j]);   // bias LAST

    __syncthreads();                     // all tile reads done -> reuse xs as agg
    float* agg = xs;                     // [e][m][c] 1024 + den [e][m] 32
    for (int t = tid; t < 1056; t += 256) agg[t] = 0.f;
    __syncthreads();

    // np l2norm: square, pairwise-32, sqrt, max(eps), per-component divide
    float sq[32];
    #pragma unroll
    for (int j = 0; j < 32; ++j) sq[j] = __fmul_rn(acc[j], acc[j]);
    float nrm = fmaxf(__fsqrt_rn(pairwise32(sq)), 1e-12f);
    float u[32];
    #pragma unroll
    for (int j = 0; j < 32; ++j) u[j] = __fdiv_rn(acc[j], nrm);

    // np einsum dot per center + sigmoid (f64, ~correctly rounded to f32)
    float bs = -1.0f; int bi = 0;
    #pragma unroll
    for (int mi = 0; mi < 8; ++mi) {
        float pr[32];
        #pragma unroll
        for (int j = 0; j < 32; ++j) pr[j] = __fmul_rn(cnp[mi * 32 + j], u[j]);
        float dot = einsum_dot32(pr);
        float z = __fadd_rn(beta, __fmul_rn(alpha, dot));
        float sm = (float)(1.0 / (1.0 + exp(-(double)z)));
        if (sm > bs) { bs = sm; bi = mi; }   // strict >: first index on ties
    }
    float s = bs;

    int sp = sp0 + spL;
    int h = sp / 1600;
    int rem = sp - h * 1600;
    int w = rem / 40;
    int d = rem - w * 40;
    int n = w * 1600 + h * 40 + d;       // h<->w swapped layout
    int b = b0 * 4 + e;
    sval[b * NSP + n] = s;
    sidx[b * NSP + n] = bi;

    float* al = &agg[(e * 8 + bi) * 32];
    #pragma unroll
    for (int j = 0; j < 32; ++j) atomicAdd(&al[j], s * acc[j]);
    atomicAdd(&agg[1024 + e * 8 + bi], s);

    __syncthreads();
    float* nr = numR + (bx & 31) * 2112 + b0 * 1056;   // replica slice
    for (int t = tid; t < 1056; t += 256)
        atomicAdd(&nr[t], agg[t]);
}

// ---- fold 32 replicas -> num[2][1024], den[2][32] (order free) -------------
__global__ __launch_bounds__(256) void reduce_nr_k(const float* __restrict__ nr,
                                                   float* __restrict__ num,
                                                   float* __restrict__ den) {
    int idx = blockIdx.x * 256 + threadIdx.x;   // 0..2303, need 2112
    if (idx >= 2112) return;
    float s0 = 0.f, s1 = 0.f, s2 = 0.f, s3 = 0.f;
    #pragma unroll
    for (int r = 0; r < 32; r += 4) {
        s0 += nr[(r + 0) * 2112 + idx];
        s1 += nr[(r + 1) * 2112 + idx];
        s2 += nr[(r + 2) * 2112 + idx];
        s3 += nr[(r + 3) * 2112 + idx];
    }
    float v = (s0 + s1) + (s2 + s3);
    int b0 = idx / 1056, t = idx - b0 * 1056;
    if (t < 1024) num[b0 * 1024 + t] = v;
    else          den[b0 * 32 + (t - 1024)] = v;
}

// ---------- w = (num+cc)/(den+1); PW[b0][o][e*8+m] = proj_w . w -------------
__global__ void wproj_k(const float* __restrict__ num, const float* __restrict__ cc,
                        const float* __restrict__ den, const float* __restrict__ pwm,
                        float* __restrict__ pw_out) {
    int bx = blockIdx.x;                 // b0*256 + o
    int b0 = bx >> 8; int o = bx & 255;
    int t = threadIdx.x;                 // 0..31 = e*8+m
    int e = t >> 3, m = t & 7;
    int b = b0 * 4 + e;
    float dv = den[b * 8 + m] + 1.0f;
    float acc = 0.f;
    for (int c = 0; c < 32; ++c)
        acc = fmaf(pwm[o * 128 + e * 32 + c],
                   num[(b * 8 + m) * 32 + c] + cc[(b * 8 + m) * 32 + c], acc);
    pw_out[(b0 * 256 + o) * 32 + t] = acc / dv;
}

// ---------- out[b0,o,n] = pb[o] + sum_e s_e * PW[o][e*8+idx_e] --------------
// grid 1000 = b0*500 + oh*250 + chunk (o split in halves of 128)
__global__ __launch_bounds__(256) void out_proj_k(
        const float* __restrict__ sval, const int* __restrict__ sidx,
        const float* __restrict__ pw, const float* __restrict__ pb,
        float* __restrict__ out) {
    __shared__ float pwl[4096];          // [128 o][32]
    int tid = threadIdx.x;
    int bx  = blockIdx.x;
    int b0  = bx / 500;
    int r   = bx - b0 * 500;
    int oh  = r / 250;
    int chunk = r - oh * 250;
    int n = chunk * 256 + tid;
    for (int k = 0; k < 16; ++k)
        pwl[k * 256 + tid] = pw[b0 * 8192 + oh * 4096 + k * 256 + tid];
    float s0 = sval[(b0 * 4 + 0) * NSP + n]; int j0 = 0  + sidx[(b0 * 4 + 0) * NSP + n];
    float s1 = sval[(b0 * 4 + 1) * NSP + n]; int j1 = 8  + sidx[(b0 * 4 + 1) * NSP + n];
    float s2 = sval[(b0 * 4 + 2) * NSP + n]; int j2 = 16 + sidx[(b0 * 4 + 2) * NSP + n];
    float s3 = sval[(b0 * 4 + 3) * NSP + n]; int j3 = 24 + sidx[(b0 * 4 + 3) * NSP + n];
    __syncthreads();
    float* ob = out + (size_t)b0 * OUTC * NSP + (size_t)oh * 128 * NSP + n;
    const float* pbh = pb + oh * 128;
    #pragma unroll 4
    for (int o = 0; o < 128; ++o) {
        const float* prw = &pwl[o * 32];
        float v = pbh[o];
        v = fmaf(s0, prw[j0], v);
        v = fmaf(s1, prw[j1], v);
        v = fmaf(s2, prw[j2], v);
        v = fmaf(s3, prw[j3], v);
        ob[(size_t)o * NSP] = v;
    }
}

extern "C" void kernel_launch(void* const* d_in, const int* in_sizes, int n_in,
                              void* d_out, int out_size, void* d_ws, size_t ws_size,
                              hipStream_t stream) {
    const float* x     = (const float*)d_in[0];
    const float* cond  = (const float*)d_in[1];
    const float* xw    = (const float*)d_in[2];
    const float* xb    = (const float*)d_in[3];
    const float* cw    = (const float*)d_in[4];
    const float* cb    = (const float*)d_in[5];
    const float* alpha = (const float*)d_in[6];
    const float* beta  = (const float*)d_in[7];
    const float* pwm   = (const float*)d_in[8];
    const float* pb    = (const float*)d_in[9];
    float* out = (float*)d_out;
    float* wsf = (float*)d_ws;

    double* dmc = (double*)(wsf + OFF_DMC);
    float* cc   = wsf + OFF_CC;
    float* num  = wsf + OFF_NUM;
    float* den  = wsf + OFF_DEN;
    float* wct  = wsf + OFF_WCT;
    float* wp4  = wsf + OFF_WXT;
    float* cnf  = wsf + OFF_CNF;
    float* part = wsf + OFF_PART;
    float* nrr  = wsf + OFF_PART;        // numR [32][2][1056] aliases dead part
    float* sv   = wsf + OFF_SVAL;
    int*   si   = (int*)(wsf + OFF_SIDX);
    float* pwq  = wsf + OFF_PW;

    transpose_k<<<64, 256, 0, stream>>>(cw, xw, wct, wp4);
    pool_cond_k<<<512, 256, 0, stream>>>(cond, dmc);
    cc_centers_k<<<64, 32, 0, stream>>>(dmc, cw, cb, cc);
    xfeat_partial_k<<<800, 256, 0, stream>>>(x, wp4, xb, part);
    xcenters_k<<<64, 32, 0, stream>>>(part, cnf);
    // part is dead now; zero its head for the 32-replica num/den accumulator
    hipMemsetAsync(nrr, 0, 32 * 2112 * sizeof(float), stream);
    fused_enc_sim_k<<<2000, 256, 0, stream>>>(cond, wct, cnf, cb, alpha, beta, sv, si, nrr);
    reduce_nr_k<<<9, 256, 0, stream>>>(nrr, num, den);
    wproj_k<<<512, 32, 0, stream>>>(num, cc, den, pwm, pwq);
    out_proj_k<<<1000, 256, 0, stream>>>(sv, si, pwq, pb, out);
}

// Round 7
// 331.600 us; speedup vs baseline: 1.5289x; 1.1638x over previous
//
#include <hip/hip_runtime.h>
#include <math.h>

#define NB0   2
#define CX    64
#define NSP   64000      // 40*40*40
#define NH    4
#define HD    32
#define NM    8
#define OUTC  256

// workspace float offsets (doubles first, 8B aligned)
#define OFF_DMC    0        // double [2][64][8]  cond block means
#define OFF_CC     2048     // float  [8][8][32]  raw cond-centers
#define OFF_NUM    4096     // float  [8][8][32]
#define OFF_DEN    6144     // float  [8][8]
#define OFF_WCT    6208     // float  [64][128]   cond_enc_w transposed
#define OFF_WXT    14400    // float  [64][32][4] x_enc_w packed [i][c][e]
#define OFF_CNF    22592    // float  [8][8][32]  normalized x-centers (np-f32 replica)
#define OFF_PART   24640    // float  [8][8][32][400] run partials; numR aliases (dead after xcenters_k)
#define OFF_SVAL   843840   // float  [8][64000]
#define OFF_SIDX   1355840  // int    [8][64000]
#define OFF_PW     1867840  // float  [2][256][32]

// numpy pairwise_sum, n==20 (r[j]=a[j]+a[8+j]; combine; tail 16..19)
__device__ __forceinline__ float pairwise20(const float* v) {
    float r[8];
    #pragma unroll
    for (int j = 0; j < 8; ++j) r[j] = __fadd_rn(v[j], v[8 + j]);
    float res = __fadd_rn(__fadd_rn(__fadd_rn(r[0], r[1]), __fadd_rn(r[2], r[3])),
                          __fadd_rn(__fadd_rn(r[4], r[5]), __fadd_rn(r[6], r[7])));
    res = __fadd_rn(res, v[16]);
    res = __fadd_rn(res, v[17]);
    res = __fadd_rn(res, v[18]);
    res = __fadd_rn(res, v[19]);
    return res;
}

// numpy pairwise_sum, n==32 (r[j]=a[j]+a[8+j]+a[16+j]+a[24+j]; combine)
__device__ __forceinline__ float pairwise32(const float* v) {
    float r[8];
    #pragma unroll
    for (int j = 0; j < 8; ++j)
        r[j] = __fadd_rn(__fadd_rn(__fadd_rn(v[j], v[8 + j]), v[16 + j]), v[24 + j]);
    return __fadd_rn(__fadd_rn(__fadd_rn(r[0], r[1]), __fadd_rn(r[2], r[3])),
                     __fadd_rn(__fadd_rn(r[4], r[5]), __fadd_rn(r[6], r[7])));
}

// numpy einsum sum_of_products f32, SSE baseline (4 lanes, 4 accumulators), n=32
__device__ __forceinline__ float einsum_dot32(const float* p) {
    float q[16];
    #pragma unroll
    for (int k = 0; k < 4; ++k) {
        #pragma unroll
        for (int l = 0; l < 4; ++l)
            q[k * 4 + l] = __fadd_rn(p[4 * k + l], p[16 + 4 * k + l]);
    }
    float rv[4];
    #pragma unroll
    for (int l = 0; l < 4; ++l)
        rv[l] = __fadd_rn(__fadd_rn(q[l], q[4 + l]), __fadd_rn(q[8 + l], q[12 + l]));
    return __fadd_rn(__fadd_rn(rv[0], rv[2]), __fadd_rn(rv[1], rv[3]));
}

// ------- cond transpose [128,64]->[64,128]; x pack [128,64]->[64][32][4] ----
__global__ void transpose_k(const float* __restrict__ cw, const float* __restrict__ xw,
                            float* __restrict__ wct, float* __restrict__ wp4) {
    int idx = blockIdx.x * 256 + threadIdx.x;   // 16384
    int sel = idx >> 13;
    int j = idx & 8191;
    if (sel == 0) {
        int i = j >> 7, o = j & 127;
        wct[j] = cw[o * 64 + i];
    } else {
        // j = (i*32 + c)*4 + e  <-  xw[(e*32+c)*64 + i]
        int e = j & 3; int t = j >> 2; int c = t & 31; int i = t >> 5;
        wp4[j] = xw[(e * 32 + c) * 64 + i];
    }
}

// ------- block means (f64) of cond over 20x20x20 blocks (smooth path) -------
__global__ __launch_bounds__(256) void pool_cond_k(const float* __restrict__ cond,
                                                   double* __restrict__ cmean) {
    int bx = blockIdx.x;                 // (b0*64+i)*4 + (hb*2+wb)
    int wh = bx & 3; int hb = wh >> 1; int wb = wh & 1;
    int i   = (bx >> 2) & 63;
    int b0  = bx >> 8;
    const float* src = cond + (size_t)(b0 * CX + i) * NSP + hb * 20 * 1600 + wb * 20 * 40;
    double s0 = 0.0, s1 = 0.0;
    for (int cell = threadIdx.x; cell < 400; cell += 256) {
        int hl = cell / 20, wl = cell - hl * 20;
        const float4* rp = (const float4*)(src + hl * 1600 + wl * 40);
        #pragma unroll
        for (int q = 0; q < 5; ++q) {
            float4 v = rp[q];
            s0 += (double)v.x; s0 += (double)v.y; s0 += (double)v.z; s0 += (double)v.w;
        }
        #pragma unroll
        for (int q = 5; q < 10; ++q) {
            float4 v = rp[q];
            s1 += (double)v.x; s1 += (double)v.y; s1 += (double)v.z; s1 += (double)v.w;
        }
    }
    #pragma unroll
    for (int k = 32; k > 0; k >>= 1) { s0 += __shfl_down(s0, k); s1 += __shfl_down(s1, k); }
    __shared__ double r0[4], r1[4];
    int wid = threadIdx.x >> 6, lane = threadIdx.x & 63;
    if (lane == 0) { r0[wid] = s0; r1[wid] = s1; }
    __syncthreads();
    if (threadIdx.x == 0) {
        double t0 = r0[0] + r0[1] + r0[2] + r0[3];
        double t1 = r1[0] + r1[1] + r1[2] + r1[3];
        double* dst = cmean + b0 * 512 + i * 8 + wb * 4 + hb * 2;  // m = wb*4+hb*2+db
        dst[0] = t0 * (1.0 / 8000.0);
        dst[1] = t1 * (1.0 / 8000.0);
    }
}

// ------- cond centers cc = enc(mean) (smooth path, f64 then f32) ------------
__global__ void cc_centers_k(const double* __restrict__ cmean,
                             const float* __restrict__ cw, const float* __restrict__ cb,
                             float* __restrict__ cc) {
    int bx = blockIdx.x;                 // b*8 + m
    int m = bx & 7; int b = bx >> 3; int b0 = b >> 2; int e = b & 3;
    int c = threadIdx.x;                 // 0..31
    int o = e * 32 + c;
    double sc = (double)cb[o];
    for (int i = 0; i < 64; ++i)
        sc = fma((double)cw[o * 64 + i], cmean[b0 * 512 + i * 8 + m], sc);
    cc[(b * 8 + m) * 32 + c] = (float)sc;
}

// ---- np-f32 replica: x_feat + pairwise20 run-partials, LDS-staged ----------
// grid 800 = (b0*8 + m)*50 + chunk; block 256 = (rg 0..7) x (c 0..31)
// Each thread computes ALL 4 heads (acc[4][20]) so x is fetched from HBM once.
// NOTE: argmax-critical path — ONLY __fadd_rn/__fmul_rn, i ascending, bias
// LAST, pairwise20.
__global__ __launch_bounds__(256, 3) void xfeat_partial_k(
        const float* __restrict__ x, const float* __restrict__ wp4,
        const float* __restrict__ xb, float* __restrict__ partial) {
    __shared__ float xs[512 * 20];       // 40 KB: row (i*8+rg), 20 floats each
    int bx = blockIdx.x;
    int chunk = bx % 50; int t2 = bx / 50;
    int m  = t2 & 7;
    int b0 = t2 >> 3;
    int qw = m >> 2, qh = (m >> 1) & 1, qd = m & 1;
    int tid = threadIdx.x;
    int lane = tid & 63, wid = tid >> 6;

    // ---- stage 40KB x tile (2560 16B slots, 40 wave-instrs over 4 waves) ----
    const float* xbase = x + (size_t)(b0 * CX) * NSP;
    for (int j = wid; j < 40; j += 4) {
        int slot = j * 64 + lane;        // = row*5 + p ; LDS byte off = slot*16
        int row = slot / 5;              // row = i*8 + rg
        int p   = slot - row * 5;
        int i   = row >> 3;
        int rg  = row & 7;
        int rglob = chunk * 8 + rg;      // 0..399, = wl*20 + hl
        int wl = rglob / 20, hl = rglob - wl * 20;
        const float* gp = xbase + (size_t)i * NSP
                        + (qh * 20 + hl) * 1600 + (qw * 20 + wl) * 40 + qd * 20 + p * 4;
        __builtin_amdgcn_global_load_lds(
            (const __attribute__((address_space(1))) void*)gp,
            (__attribute__((address_space(3))) void*)(xs + slot * 4),
            16, 0, 0);
    }
    __syncthreads();                     // drains vmcnt before LDS reads

    int c  = tid & 31;
    int rg = tid >> 5;                   // 0..7

    float acc[4][20];
    #pragma unroll
    for (int e = 0; e < 4; ++e)
        #pragma unroll
        for (int d = 0; d < 20; ++d) acc[e][d] = 0.f;

    const float* xrow0 = xs + rg * 20;
    for (int i = 0; i < 64; ++i) {
        float4 wv = *(const float4*)(wp4 + ((i * 32 + c) << 2));  // [i][c][e], L2-hot
        float xv[20];
        #pragma unroll
        for (int dd = 0; dd < 5; ++dd)
            *(float4*)(xv + dd * 4) = *(const float4*)(xrow0 + i * 160 + dd * 4);
        #pragma unroll
        for (int d = 0; d < 20; ++d) {   // np order: mul then add, i ascending
            acc[0][d] = __fadd_rn(acc[0][d], __fmul_rn(wv.x, xv[d]));
            acc[1][d] = __fadd_rn(acc[1][d], __fmul_rn(wv.y, xv[d]));
            acc[2][d] = __fadd_rn(acc[2][d], __fmul_rn(wv.z, xv[d]));
            acc[3][d] = __fadd_rn(acc[3][d], __fmul_rn(wv.w, xv[d]));
        }
    }

    int rglob = chunk * 8 + rg;
    size_t obase = ((size_t)((b0 * 4) * 8 + m) * 32 + c) * 400 + rglob;
    #pragma unroll
    for (int e = 0; e < 4; ++e) {
        float bias = xb[e * 32 + c];
        float feat[20];
        #pragma unroll
        for (int d = 0; d < 20; ++d) feat[d] = __fadd_rn(acc[e][d], bias);  // bias LAST
        partial[obase + (size_t)e * 102400] = pairwise20(feat);
    }
}

// ---- np-f32 replica: 400-run chain (h-inner,w-outer order) + mean + l2norm -
__global__ void xcenters_k(const float* __restrict__ partial, float* __restrict__ cnf) {
    int bx = blockIdx.x;                 // b*8 + m
    int c = threadIdx.x;                 // 0..31
    const float* pp = partial + ((size_t)(bx * 32 + c)) * 400;
    float acc = 0.f;
    for (int r = 0; r < 400; ++r) acc = __fadd_rn(acc, pp[r]);   // r ascending
    float mean = __fdiv_rn(acc, 8000.0f);
    __shared__ float mm[32];
    mm[c] = mean;
    __syncthreads();
    float sq[32];
    #pragma unroll
    for (int j = 0; j < 32; ++j) sq[j] = __fmul_rn(mm[j], mm[j]);
    float nrm = fmaxf(__fsqrt_rn(pairwise32(sq)), 1e-12f);
    cnf[bx * 32 + c] = __fdiv_rn(mean, nrm);
}

// ---- fused: np-f32-replica cond encode + l2norm + sim/argmax + num/den -----
// grid 2000 = b0*1000 + grp (64 voxels per block; wave e handles head e).
// Proven FP DAG for s/bi, untouched. CHANGE vs R6: the per-voxel LDS
// atomicAdd aggregation is GONE (its agg layout put every j in bank j for all
// (e,bi) -> every ds_add was a guaranteed 64-deep same-bank serialization on
// the CU-shared LDS pipe -- the invariant ~137us across R0/R4/R6). Replaced
// by: dump p=s*acc,s,bi to lds2[256][36] (stride 144B, 16B-aligned, b128-able;
// reads are 8-addr x 8-broadcast = conflict-free), then each wave transpose-
// reduces its own 64 voxels (lane owns (m=spL>>3, jg=spL&7)), then 4 global
// replica atomics per lane. num/den order was already nondeterministic.
__global__ __launch_bounds__(256, 3) void fused_enc_sim_k(
        const float* __restrict__ cond, const float* __restrict__ wct,
        const float* __restrict__ cnf, const float* __restrict__ cbias,
        const float* __restrict__ alpha_p, const float* __restrict__ beta_p,
        float* __restrict__ sval, int* __restrict__ sidx,
        float* __restrict__ numR) {
    __shared__ float lds2[9216];         // 36 KB dump [256][36]; first 16KB alias staging tile
    __shared__ float cns[1024];          // [e][m][c]
    float* xs = lds2;                    // [i][vox] cond tile 16KB (dead before dump)
    int tid = threadIdx.x;
    int bx  = blockIdx.x;
    int b0  = bx / 1000;
    int grp = bx - b0 * 1000;
    int sp0 = grp * 64;
    int spL = tid & 63;
    int lane = tid & 63, wid = tid >> 6;
    int e = __builtin_amdgcn_readfirstlane(tid >> 6);
    float alpha = alpha_p[0], beta = beta_p[0];
    const float* wt = wct + e * 32;      // wave-uniform -> scalar loads
    const float* bp = cbias + e * 32;

    // ---- stage cond tile [64 ch][64 vox] (1024 16B slots, 4 instrs/wave) ----
    const float* cbase = cond + (size_t)b0 * CX * NSP + sp0;
    for (int j = wid; j < 16; j += 4) {
        int slot = j * 64 + lane;        // LDS byte off = slot*16 (linear, m104)
        int i  = slot >> 4;              // channel (16 slots per 256B row)
        int vq = slot & 15;              // 16B chunk within row
        const float* gp = cbase + (size_t)i * NSP + vq * 4;
        __builtin_amdgcn_global_load_lds(
            (const __attribute__((address_space(1))) void*)gp,
            (__attribute__((address_space(3))) void*)(xs + slot * 4),
            16, 0, 0);
    }
    for (int t = tid; t < 1024; t += 256) cns[t] = cnf[b0 * 1024 + t];
    const float* cnp = cns + e * 256;
    __syncthreads();                     // drains vmcnt; tile + cns ready

    // np einsum order: acc=0; += w*x via separate mul,add (intrinsics — NO FMA)
    float acc[32];
    #pragma unroll
    for (int j = 0; j < 32; ++j) acc[j] = 0.f;
    for (int i = 0; i < 64; ++i) {
        float xv = xs[i * 64 + spL];     // ds_read_b32, 2 lanes/bank = free
        const float* wr = wt + i * 128;
        #pragma unroll
        for (int j = 0; j < 32; ++j) acc[j] = __fadd_rn(acc[j], __fmul_rn(wr[j], xv));
    }
    #pragma unroll
    for (int j = 0; j < 32; ++j) acc[j] = __fadd_rn(acc[j], bp[j]);   // bias LAST

    // np l2norm: square, pairwise-32, sqrt, max(eps), per-component divide
    float sq[32];
    #pragma unroll
    for (int j = 0; j < 32; ++j) sq[j] = __fmul_rn(acc[j], acc[j]);
    float nrm = fmaxf(__fsqrt_rn(pairwise32(sq)), 1e-12f);
    float u[32];
    #pragma unroll
    for (int j = 0; j < 32; ++j) u[j] = __fdiv_rn(acc[j], nrm);

    // np einsum dot per center + sigmoid (f64, ~correctly rounded to f32)
    float bs = -1.0f; int bi = 0;
    #pragma unroll
    for (int mi = 0; mi < 8; ++mi) {
        float pr[32];
        #pragma unroll
        for (int j = 0; j < 32; ++j) pr[j] = __fmul_rn(cnp[mi * 32 + j], u[j]);
        float dot = einsum_dot32(pr);
        float z = __fadd_rn(beta, __fmul_rn(alpha, dot));
        float sm = (float)(1.0 / (1.0 + exp(-(double)z)));
        if (sm > bs) { bs = sm; bi = mi; }   // strict >: first index on ties
    }
    float s = bs;

    int sp = sp0 + spL;
    int h = sp / 1600;
    int rem = sp - h * 1600;
    int w = rem / 40;
    int d = rem - w * 40;
    int n = w * 1600 + h * 40 + d;       // h<->w swapped layout
    int b = b0 * 4 + e;
    sval[b * NSP + n] = s;
    sidx[b * NSP + n] = bi;

    __syncthreads();                     // ALL waves done reading xs tile -> reuse as dump

    // ---- dump p = s*acc, s, bi (row stride 36 floats = 144B, 16B aligned) ----
    int rowb = tid * 36;
    #pragma unroll
    for (int j = 0; j < 32; ++j) lds2[rowb + j] = __fmul_rn(s, acc[j]);
    lds2[rowb + 32] = s;
    lds2[rowb + 33] = __int_as_float(bi);

    __syncthreads();                     // dump visible to all lanes

    // ---- per-wave transpose reduce: lane owns (mo = spL>>3, jg = spL&7) ----
    int mo = spL >> 3;
    int jg = spL & 7;
    int baseW = e * 2304;                // e*64 rows * 36
    float s0a = 0.f, s1a = 0.f, s2a = 0.f, s3a = 0.f, dsum = 0.f;
    for (int v = 0; v < 64; ++v) {
        int rb = baseW + v * 36;
        float sv   = lds2[rb + 32];              // broadcast (same addr all lanes)
        int   biv  = __float_as_int(lds2[rb + 33]);
        const float* pv = &lds2[rb + jg * 4];    // 8 addrs x 8-lane broadcast
        float p0 = pv[0], p1 = pv[1], p2 = pv[2], p3 = pv[3];
        bool hit = (biv == mo);
        s0a += hit ? p0 : 0.f;
        s1a += hit ? p1 : 0.f;
        s2a += hit ? p2 : 0.f;
        s3a += hit ? p3 : 0.f;
        dsum += hit ? sv : 0.f;
    }

    // ---- global replica atomics (same 1056/block as before) ----
    float* nr = numR + (bx & 31) * 2112 + b0 * 1056;
    int ob = (e * 8 + mo) * 32 + jg * 4;
    atomicAdd(&nr[ob + 0], s0a);
    atomicAdd(&nr[ob + 1], s1a);
    atomicAdd(&nr[ob + 2], s2a);
    atomicAdd(&nr[ob + 3], s3a);
    if (jg == 0) atomicAdd(&nr[1024 + e * 8 + mo], dsum);
}

// ---- fold 32 replicas -> num[2][1024], den[2][32] (order free) -------------
__global__ __launch_bounds__(256) void reduce_nr_k(const float* __restrict__ nr,
                                                   float* __restrict__ num,
                                                   float* __restrict__ den) {
    int idx = blockIdx.x * 256 + threadIdx.x;   // 0..2303, need 2112
    if (idx >= 2112) return;
    float s0 = 0.f, s1 = 0.f, s2 = 0.f, s3 = 0.f;
    #pragma unroll
    for (int r = 0; r < 32; r += 4) {
        s0 += nr[(r + 0) * 2112 + idx];
        s1 += nr[(r + 1) * 2112 + idx];
        s2 += nr[(r + 2) * 2112 + idx];
        s3 += nr[(r + 3) * 2112 + idx];
    }
    float v = (s0 + s1) + (s2 + s3);
    int b0 = idx / 1056, t = idx - b0 * 1056;
    if (t < 1024) num[b0 * 1024 + t] = v;
    else          den[b0 * 32 + (t - 1024)] = v;
}

// ---------- w = (num+cc)/(den+1); PW[b0][o][e*8+m] = proj_w . w -------------
__global__ void wproj_k(const float* __restrict__ num, const float* __restrict__ cc,
                        const float* __restrict__ den, const float* __restrict__ pwm,
                        float* __restrict__ pw_out) {
    int bx = blockIdx.x;                 // b0*256 + o
    int b0 = bx >> 8; int o = bx & 255;
    int t = threadIdx.x;                 // 0..31 = e*8+m
    int e = t >> 3, m = t & 7;
    int b = b0 * 4 + e;
    float dv = den[b * 8 + m] + 1.0f;
    float acc = 0.f;
    for (int c = 0; c < 32; ++c)
        acc = fmaf(pwm[o * 128 + e * 32 + c],
                   num[(b * 8 + m) * 32 + c] + cc[(b * 8 + m) * 32 + c], acc);
    pw_out[(b0 * 256 + o) * 32 + t] = acc / dv;
}

// ---------- out[b0,o,n] = pb[o] + sum_e s_e * PW[o][e*8+idx_e] --------------
// grid 1000 = b0*500 + oh*250 + chunk (o split in halves of 128)
__global__ __launch_bounds__(256) void out_proj_k(
        const float* __restrict__ sval, const int* __restrict__ sidx,
        const float* __restrict__ pw, const float* __restrict__ pb,
        float* __restrict__ out) {
    __shared__ float pwl[4096];          // [128 o][32]
    int tid = threadIdx.x;
    int bx  = blockIdx.x;
    int b0  = bx / 500;
    int r   = bx - b0 * 500;
    int oh  = r / 250;
    int chunk = r - oh * 250;
    int n = chunk * 256 + tid;
    for (int k = 0; k < 16; ++k)
        pwl[k * 256 + tid] = pw[b0 * 8192 + oh * 4096 + k * 256 + tid];
    float s0 = sval[(b0 * 4 + 0) * NSP + n]; int j0 = 0  + sidx[(b0 * 4 + 0) * NSP + n];
    float s1 = sval[(b0 * 4 + 1) * NSP + n]; int j1 = 8  + sidx[(b0 * 4 + 1) * NSP + n];
    float s2 = sval[(b0 * 4 + 2) * NSP + n]; int j2 = 16 + sidx[(b0 * 4 + 2) * NSP + n];
    float s3 = sval[(b0 * 4 + 3) * NSP + n]; int j3 = 24 + sidx[(b0 * 4 + 3) * NSP + n];
    __syncthreads();
    float* ob = out + (size_t)b0 * OUTC * NSP + (size_t)oh * 128 * NSP + n;
    const float* pbh = pb + oh * 128;
    #pragma unroll 4
    for (int o = 0; o < 128; ++o) {
        const float* prw = &pwl[o * 32];
        float v = pbh[o];
        v = fmaf(s0, prw[j0], v);
        v = fmaf(s1, prw[j1], v);
        v = fmaf(s2, prw[j2], v);
        v = fmaf(s3, prw[j3], v);
        ob[(size_t)o * NSP] = v;
    }
}

extern "C" void kernel_launch(void* const* d_in, const int* in_sizes, int n_in,
                              void* d_out, int out_size, void* d_ws, size_t ws_size,
                              hipStream_t stream) {
    const float* x     = (const float*)d_in[0];
    const float* cond  = (const float*)d_in[1];
    const float* xw    = (const float*)d_in[2];
    const float* xb    = (const float*)d_in[3];
    const float* cw    = (const float*)d_in[4];
    const float* cb    = (const float*)d_in[5];
    const float* alpha = (const float*)d_in[6];
    const float* beta  = (const float*)d_in[7];
    const float* pwm   = (const float*)d_in[8];
    const float* pb    = (const float*)d_in[9];
    float* out = (float*)d_out;
    float* wsf = (float*)d_ws;

    double* dmc = (double*)(wsf + OFF_DMC);
    float* cc   = wsf + OFF_CC;
    float* num  = wsf + OFF_NUM;
    float* den  = wsf + OFF_DEN;
    float* wct  = wsf + OFF_WCT;
    float* wp4  = wsf + OFF_WXT;
    float* cnf  = wsf + OFF_CNF;
    float* part = wsf + OFF_PART;
    float* nrr  = wsf + OFF_PART;        // numR [32][2][1056] aliases dead part
    float* sv   = wsf + OFF_SVAL;
    int*   si   = (int*)(wsf + OFF_SIDX);
    float* pwq  = wsf + OFF_PW;

    transpose_k<<<64, 256, 0, stream>>>(cw, xw, wct, wp4);
    pool_cond_k<<<512, 256, 0, stream>>>(cond, dmc);
    cc_centers_k<<<64, 32, 0, stream>>>(dmc, cw, cb, cc);
    xfeat_partial_k<<<800, 256, 0, stream>>>(x, wp4, xb, part);
    xcenters_k<<<64, 32, 0, stream>>>(part, cnf);
    // part is dead now; zero its head for the 32-replica num/den accumulator
    hipMemsetAsync(nrr, 0, 32 * 2112 * sizeof(float), stream);
    fused_enc_sim_k<<<2000, 256, 0, stream>>>(cond, wct, cnf, cb, alpha, beta, sv, si, nrr);
    reduce_nr_k<<<9, 256, 0, stream>>>(nrr, num, den);
    wproj_k<<<512, 32, 0, stream>>>(num, cc, den, pwm, pwq);
    out_proj_k<<<1000, 256, 0, stream>>>(sv, si, pwq, pb, out);
}